// Round 7
// baseline (4172.613 us; speedup 1.0000x reference)
//
#include <hip/hip_runtime.h>
#include <hip/hip_bf16.h>

// ViT forward, MI355X. Round-3 m97-style gemm_bt (best measured) for qkv/proj/
// patch; NEW fused FFN kernel (FFN1+gelu+FFN2+residual+LN in one launch,
// h never touches HBM); fused flash attention; f32 residual stream.

typedef unsigned short u16;
typedef __hip_bfloat16 bf16;
typedef __bf16 bf16x8 __attribute__((ext_vector_type(8)));
typedef float f32x4 __attribute__((ext_vector_type(4)));

typedef const __attribute__((address_space(1))) void* gas_ptr;
typedef __attribute__((address_space(3))) void* las_ptr;

#define TOKENS 577
#define TPAD   640
#define DMODEL 512
#define SM_SCALE 0.08838834764831845f   /* 128^-0.5 */

static __device__ __forceinline__ u16 f2b(float v) {
    bf16 t = __float2bfloat16(v);
    return *(u16*)&t;
}

// ---------------------------------------------------------------------------
// Round-3 GEMM (measured best for this workload): 128x128 tile, BK=64,
// global_load_lds staging, 2 barriers per K-step.
// C[M,N] = A[M,K] @ Bt[N,K]^T. OUTMODE 0: plain. 1: patch-embed epilogue.
// ---------------------------------------------------------------------------
template<int OUTMODE>
__global__ __launch_bounds__(256)
void gemm_bt(const u16* __restrict__ A, int lda,
             const u16* __restrict__ Bt, int ldb,
             float* __restrict__ Cf, bf16* __restrict__ Cb, int ldc,
             const float* __restrict__ bias, const float* __restrict__ pos,
             int K, int rows_valid)
{
    __shared__ u16 As[128 * 64];
    __shared__ u16 Bs[128 * 64];
    const int tid  = threadIdx.x;
    const int w    = tid >> 6;
    const int lane = tid & 63;
    const u16* Ab = A + (long)blockIdx.y * 128 * lda;
    const u16* Bb = Bt + (long)blockIdx.x * 128 * ldb;
    const int srow = w * 8 + (lane >> 3);
    const int scol = (lane & 7) * 8;
    const int wr = w >> 1, wc = w & 1;
    const int lr = lane & 15, lg = lane >> 4;
    f32x4 acc[4][4] = {};

    for (int kt = 0; kt < K; kt += 64) {
#pragma unroll
        for (int i = 0; i < 4; ++i) {
            const u16* ag = Ab + (long)(i * 32 + srow) * lda + kt + scol;
            const u16* bg = Bb + (long)(i * 32 + srow) * ldb + kt + scol;
            __builtin_amdgcn_global_load_lds((gas_ptr)ag, (las_ptr)&As[(i * 32 + w * 8) * 64], 16, 0, 0);
            __builtin_amdgcn_global_load_lds((gas_ptr)bg, (las_ptr)&Bs[(i * 32 + w * 8) * 64], 16, 0, 0);
        }
        __syncthreads();
#pragma unroll
        for (int kk = 0; kk < 2; ++kk) {
            const int ko = kk * 32 + lg * 8;
            bf16x8 af[4], bv[4];
#pragma unroll
            for (int m = 0; m < 4; ++m)
                af[m] = *(const bf16x8*)&As[(wr * 64 + m * 16 + lr) * 64 + ko];
#pragma unroll
            for (int n = 0; n < 4; ++n)
                bv[n] = *(const bf16x8*)&Bs[(wc * 64 + n * 16 + lr) * 64 + ko];
#pragma unroll
            for (int m = 0; m < 4; ++m)
#pragma unroll
                for (int n = 0; n < 4; ++n)
                    acc[m][n] = __builtin_amdgcn_mfma_f32_16x16x32_bf16(af[m], bv[n], acc[m][n], 0, 0, 0);
        }
        __syncthreads();
    }

    const int cbase = blockIdx.x * 128 + wc * 64;
    const int rbase = blockIdx.y * 128 + wr * 64;
#pragma unroll
    for (int n = 0; n < 4; ++n) {
        const int c = cbase + n * 16 + lr;
        const float bval = bias ? bias[c] : 0.0f;
#pragma unroll
        for (int m = 0; m < 4; ++m) {
#pragma unroll
            for (int j = 0; j < 4; ++j) {
                const int r = rbase + m * 16 + lg * 4 + j;
                if (r >= rows_valid) continue;
                float v = acc[m][n][j] + bval;
                long idx;
                if constexpr (OUTMODE == 1) {
                    const int pb = r / 576, pt = r - pb * 576;
                    v += pos[(long)(1 + pt) * DMODEL + c];
                    idx = (long)(pb * TOKENS + 1 + pt) * ldc + c;
                } else {
                    idx = (long)r * ldc + c;
                }
                if (Cf) Cf[idx] = v;
                if (Cb) Cb[idx] = __float2bfloat16(v);
            }
        }
    }
}

// ---------------------------------------------------------------------------
// Fused FFN: t = gelu(y @ W1 + bb1) @ W2 + bb2 + y  -> LayerNorm -> tokf, xb.
// Block = 32 M-rows, 512 threads = 8 waves. y (32x512 bf16) staged once in LDS
// (XOR-swizzled octets). 16 chunks of 128 h-cols: GEMM1 (W1 frags streamed
// L2->VGPR, depth-4) -> gelu -> h in LDS (swizzled) -> GEMM2 accumulate into
// persistent tacc (32 f32/thread). h never touches HBM. LN in epilogue.
// ---------------------------------------------------------------------------
__global__ __launch_bounds__(512)
void ffn_fused(const u16* __restrict__ y16, const float* __restrict__ yres,
               const u16* __restrict__ w1T, const u16* __restrict__ w2T,
               const float* __restrict__ bb1, const float* __restrict__ bb2,
               const float* __restrict__ gam, const float* __restrict__ bet,
               float* __restrict__ outf, bf16* __restrict__ outb, int Mrows)
{
    __shared__ u16 y_lds[32 * 512];     // 32 KB, swizzled octets
    __shared__ u16 h_lds[32 * 128];     // 8 KB, col ^ ((row&7)<<3)
    __shared__ float redS[8][32];
    __shared__ float redQ[8][32];
    const int tid = threadIdx.x, wid = tid >> 6, lane = tid & 63;
    const int lr = lane & 15, lg = lane >> 4;
    const long row0 = (long)blockIdx.x * 32;

    // stage y rows (clamped), pre-swizzled global source -> linear LDS dst
#pragma unroll
    for (int i = 0; i < 4; ++i) {
        const int g = i * 512 + tid;          // octet index 0..2047
        const int r = g >> 6, sl = g & 63;
        const int so = (sl & ~7) | ((sl & 7) ^ (r & 7));
        long sr = row0 + r; if (sr >= Mrows) sr = Mrows - 1;
        __builtin_amdgcn_global_load_lds(
            (gas_ptr)(y16 + sr * 512 + so * 8),
            (las_ptr)&y_lds[g * 8], 16, 0, 0);
    }
    __syncthreads();

    f32x4 tacc[2][4] = {};
    const int tbase = wid * 64;               // this wave's t-col base

    for (int ck = 0; ck < 16; ++ck) {
        // ---- GEMM1: h chunk 32 x 128 (wave owns 16 h-cols) ----
        f32x4 acc1[2] = {};
        const u16* b1p = w1T + (long)(ck * 128 + wid * 16 + lr) * 512 + lg * 8;
        bf16x8 bb1r[4];
#pragma unroll
        for (int p = 0; p < 4; ++p) bb1r[p] = *(const bf16x8*)&b1p[p * 32];
#pragma unroll
        for (int kf = 0; kf < 16; ++kf) {
            bf16x8 af[2];
#pragma unroll
            for (int m = 0; m < 2; ++m) {
                const int rr = m * 16 + lr;
                const int o = kf * 4 + lg;
                const int so = (o & ~7) | ((o & 7) ^ (rr & 7));
                af[m] = *(const bf16x8*)&y_lds[rr * 512 + so * 8];
            }
            const bf16x8 bv = bb1r[kf & 3];
            if (kf + 4 < 16) bb1r[kf & 3] = *(const bf16x8*)&b1p[(kf + 4) * 32];
            __builtin_amdgcn_s_setprio(1);
#pragma unroll
            for (int m = 0; m < 2; ++m)
                acc1[m] = __builtin_amdgcn_mfma_f32_16x16x32_bf16(af[m], bv, acc1[m], 0, 0, 0);
            __builtin_amdgcn_s_setprio(0);
        }
        // gelu -> h_lds (C layout: row = m*16+lg*4+j, col = wid*16+lr)
#pragma unroll
        for (int m = 0; m < 2; ++m)
#pragma unroll
            for (int j = 0; j < 4; ++j) {
                const int rr = m * 16 + lg * 4 + j;
                const int cc = wid * 16 + lr;
                float v = acc1[m][j] + bb1[ck * 128 + cc];
                v = 0.5f * v * (1.0f + erff(v * 0.70710678118654752f));
                h_lds[rr * 128 + (cc ^ ((rr & 7) << 3))] = f2b(v);
            }
        __syncthreads();

        // ---- GEMM2 partial: tacc += h @ W2[ck*128 .. +127, :] ----
        const u16* b2p[4];
        bf16x8 bb2r[2][4];
#pragma unroll
        for (int n = 0; n < 4; ++n) {
            b2p[n] = w2T + (long)(tbase + n * 16 + lr) * 2048 + ck * 128 + lg * 8;
            bb2r[0][n] = *(const bf16x8*)&b2p[n][0];
            bb2r[1][n] = *(const bf16x8*)&b2p[n][32];
        }
#pragma unroll
        for (int kf = 0; kf < 4; ++kf) {
            bf16x8 ha[2];
#pragma unroll
            for (int m = 0; m < 2; ++m) {
                const int rr = m * 16 + lr;
                const int c0 = (kf * 32 + lg * 8) ^ ((rr & 7) << 3);
                ha[m] = *(const bf16x8*)&h_lds[rr * 128 + c0];
            }
            __builtin_amdgcn_s_setprio(1);
#pragma unroll
            for (int n = 0; n < 4; ++n) {
                const bf16x8 bv = bb2r[kf & 1][n];
#pragma unroll
                for (int m = 0; m < 2; ++m)
                    tacc[m][n] = __builtin_amdgcn_mfma_f32_16x16x32_bf16(ha[m], bv, tacc[m][n], 0, 0, 0);
            }
            __builtin_amdgcn_s_setprio(0);
            if (kf + 2 < 4) {
#pragma unroll
                for (int n = 0; n < 4; ++n)
                    bb2r[kf & 1][n] = *(const bf16x8*)&b2p[n][(kf + 2) * 32];
            }
        }
        __syncthreads();   // h_lds reusable next chunk
    }

    // ---- epilogue: + bb2 + residual, LayerNorm, write tokf (f32) + xb (bf16)
    float bv2[4];
#pragma unroll
    for (int n = 0; n < 4; ++n) bv2[n] = bb2[tbase + n * 16 + lr];
    float ps[2][4], pq[2][4];
#pragma unroll
    for (int m = 0; m < 2; ++m)
#pragma unroll
        for (int j = 0; j < 4; ++j) {
            const long r = row0 + m * 16 + lg * 4 + j;
            float s = 0.f, q = 0.f;
#pragma unroll
            for (int n = 0; n < 4; ++n) {
                float v = tacc[m][n][j] + bv2[n];
                if (r < Mrows) v += yres[r * DMODEL + tbase + n * 16 + lr];
                tacc[m][n][j] = v;
                s += v; q += v * v;
            }
            ps[m][j] = s; pq[m][j] = q;
        }
#pragma unroll
    for (int o = 1; o < 16; o <<= 1)
#pragma unroll
        for (int m = 0; m < 2; ++m)
#pragma unroll
            for (int j = 0; j < 4; ++j) {
                ps[m][j] += __shfl_xor(ps[m][j], o);
                pq[m][j] += __shfl_xor(pq[m][j], o);
            }
    if (lr == 0) {
#pragma unroll
        for (int m = 0; m < 2; ++m)
#pragma unroll
            for (int j = 0; j < 4; ++j) {
                redS[wid][m * 16 + lg * 4 + j] = ps[m][j];
                redQ[wid][m * 16 + lg * 4 + j] = pq[m][j];
            }
    }
    __syncthreads();
    if (tid < 32) {
        float s = 0.f, q = 0.f;
#pragma unroll
        for (int w = 0; w < 8; ++w) { s += redS[w][tid]; q += redQ[w][tid]; }
        const float mean = s * (1.f / 512.f);
        const float var = q * (1.f / 512.f) - mean * mean;
        redS[0][tid] = mean;
        redQ[0][tid] = rsqrtf(var + 1e-5f);
    }
    __syncthreads();
#pragma unroll
    for (int m = 0; m < 2; ++m)
#pragma unroll
        for (int j = 0; j < 4; ++j) {
            const int ri = m * 16 + lg * 4 + j;
            const long r = row0 + ri;
            if (r >= Mrows) continue;
            const float mean = redS[0][ri], rs = redQ[0][ri];
#pragma unroll
            for (int n = 0; n < 4; ++n) {
                const int c = tbase + n * 16 + lr;
                const float o = (tacc[m][n][j] - mean) * rs * gam[c] + bet[c];
                outf[r * DMODEL + c] = o;
                outb[r * DMODEL + c] = __float2bfloat16(o);
            }
        }
}

// ---------------------------------------------------------------------------
// Fused flash attention. Grid: (5 q-tiles, NP pairs). 256 threads = 4 waves.
// qkv layout (permuted): [row][ kk*512 + h*128 + d ], row = b*577 + t (+pad).
// ---------------------------------------------------------------------------
__global__ __launch_bounds__(256, 2)
void attn_flash(const u16* __restrict__ qkv, const u16* __restrict__ vhT,
                bf16* __restrict__ ob)
{
    __shared__ u16 ldsA[128 * 128];   // K tile, then P tile
    __shared__ u16 ldsB[128 * 128];   // V^T tile [d][kv]
    const int tid = threadIdx.x;
    const int w = tid >> 6, lane = tid & 63;
    const int lr = lane & 15, lg = lane >> 4;
    const int pair = blockIdx.y;
    const int b = pair >> 2, h = pair & 3;
    const int q0 = blockIdx.x * 128;
    const long rowbase = (long)b * TOKENS;

    bf16x8 qf[2][4];
#pragma unroll
    for (int m = 0; m < 2; ++m)
#pragma unroll
        for (int kf = 0; kf < 4; ++kf) {
            const long r = rowbase + q0 + w * 32 + m * 16 + lr;
            qf[m][kf] = *(const bf16x8*)&qkv[r * 1536 + h * 128 + kf * 32 + lg * 8];
        }

    float mrun[2][4], lrun[2][4];
#pragma unroll
    for (int m = 0; m < 2; ++m)
#pragma unroll
        for (int j = 0; j < 4; ++j) { mrun[m][j] = -1e30f; lrun[m][j] = 0.f; }
    f32x4 oacc[2][8] = {};

    for (int kv0 = 0; kv0 < TPAD; kv0 += 128) {
        {
            const u16* kg = qkv + (rowbase + kv0) * 1536 + 512 + h * 128;
            const u16* vg = vhT + ((long)pair * 128) * TPAD + kv0;
#pragma unroll
            for (int p = 0; p < 8; ++p) {
                const int i = p * 16 + w * 4 + lg;
                __builtin_amdgcn_global_load_lds((gas_ptr)(kg + (long)i * 1536 + lr * 8),
                                                 (las_ptr)&ldsA[(p * 16 + w * 4) * 128], 16, 0, 0);
                __builtin_amdgcn_global_load_lds((gas_ptr)(vg + (long)i * TPAD + lr * 8),
                                                 (las_ptr)&ldsB[(p * 16 + w * 4) * 128], 16, 0, 0);
            }
        }
        __syncthreads();

        f32x4 s[2][8] = {};
#pragma unroll
        for (int kf = 0; kf < 4; ++kf) {
            bf16x8 bv[8];
#pragma unroll
            for (int n = 0; n < 8; ++n)
                bv[n] = *(const bf16x8*)&ldsA[(n * 16 + lr) * 128 + kf * 32 + lg * 8];
            __builtin_amdgcn_s_setprio(1);
#pragma unroll
            for (int m = 0; m < 2; ++m)
#pragma unroll
                for (int n = 0; n < 8; ++n)
                    s[m][n] = __builtin_amdgcn_mfma_f32_16x16x32_bf16(qf[m][kf], bv[n], s[m][n], 0, 0, 0);
            __builtin_amdgcn_s_setprio(0);
        }

        float sc[2][4];
#pragma unroll
        for (int m = 0; m < 2; ++m)
#pragma unroll
            for (int jj = 0; jj < 4; ++jj) {
                float mx = mrun[m][jj];
#pragma unroll
                for (int n = 0; n < 8; ++n) {
                    const int col = kv0 + n * 16 + lr;
                    float v = s[m][n][jj] * SM_SCALE;
                    v = (col < TOKENS) ? v : -1e30f;
                    s[m][n][jj] = v;
                    mx = fmaxf(mx, v);
                }
#pragma unroll
                for (int o = 1; o < 16; o <<= 1) mx = fmaxf(mx, __shfl_xor(mx, o));
                const float f = __expf(mrun[m][jj] - mx);
                sc[m][jj] = f;
                float sum = 0.f;
#pragma unroll
                for (int n = 0; n < 8; ++n) {
                    const float p = __expf(s[m][n][jj] - mx);
                    s[m][n][jj] = p;
                    sum += p;
                }
#pragma unroll
                for (int o = 1; o < 16; o <<= 1) sum += __shfl_xor(sum, o);
                lrun[m][jj] = lrun[m][jj] * f + sum;
                mrun[m][jj] = mx;
            }
#pragma unroll
        for (int m = 0; m < 2; ++m)
#pragma unroll
            for (int n = 0; n < 8; ++n)
#pragma unroll
                for (int jj = 0; jj < 4; ++jj) oacc[m][n][jj] *= sc[m][jj];

        __syncthreads();
#pragma unroll
        for (int m = 0; m < 2; ++m)
#pragma unroll
            for (int n = 0; n < 8; ++n)
#pragma unroll
                for (int jj = 0; jj < 4; ++jj)
                    ldsA[(w * 32 + m * 16 + lg * 4 + jj) * 128 + n * 16 + lr] = f2b(s[m][n][jj]);
        __syncthreads();

#pragma unroll
        for (int kf = 0; kf < 4; ++kf) {
            bf16x8 pa[2];
#pragma unroll
            for (int m = 0; m < 2; ++m)
                pa[m] = *(const bf16x8*)&ldsA[(w * 32 + m * 16 + lr) * 128 + kf * 32 + lg * 8];
            __builtin_amdgcn_s_setprio(1);
#pragma unroll
            for (int n = 0; n < 8; ++n) {
                const bf16x8 vb = *(const bf16x8*)&ldsB[(n * 16 + lr) * 128 + kf * 32 + lg * 8];
#pragma unroll
                for (int m = 0; m < 2; ++m)
                    oacc[m][n] = __builtin_amdgcn_mfma_f32_16x16x32_bf16(pa[m], vb, oacc[m][n], 0, 0, 0);
            }
            __builtin_amdgcn_s_setprio(0);
        }
        __syncthreads();
    }

#pragma unroll
    for (int m = 0; m < 2; ++m)
#pragma unroll
        for (int jj = 0; jj < 4; ++jj) {
            const float inv = 1.f / lrun[m][jj];
            const int q = q0 + w * 32 + m * 16 + lg * 4 + jj;
            if (q >= TOKENS) continue;
#pragma unroll
            for (int n = 0; n < 8; ++n)
                ob[(rowbase + q) * DMODEL + h * 128 + n * 16 + lr] =
                    __float2bfloat16(oacc[m][n][jj] * inv);
        }
}

// ---------------------------------------------------------------------------
// Weight transpose + f32->bf16:  WT[n][k] = bf16(W[k][n]).
// QKVPERM: output row n' = kk*512 + h*128 + d  for original col n = d*12+kk*4+h
// ---------------------------------------------------------------------------
template<bool QKVPERM>
__global__ __launch_bounds__(256)
void wtrans(const float* __restrict__ W, bf16* __restrict__ WT, int K, int N)
{
    __shared__ float tile[32][33];
    const int n0 = blockIdx.x * 32, k0 = blockIdx.y * 32;
    const int tx = threadIdx.x & 31, ty = threadIdx.x >> 5;
#pragma unroll
    for (int i = 0; i < 4; ++i)
        tile[ty + i * 8][tx] = W[(long)(k0 + ty + i * 8) * N + n0 + tx];
    __syncthreads();
#pragma unroll
    for (int i = 0; i < 4; ++i) {
        int n = n0 + ty + i * 8;
        if constexpr (QKVPERM) {
            const int d = n / 12, r = n % 12;
            n = (r >> 2) * 512 + (r & 3) * 128 + d;
        }
        WT[(long)n * K + k0 + tx] = __float2bfloat16(tile[tx][ty + i * 8]);
    }
}

// ---------------------------------------------------------------------------
// Patch gather: img (Bc,3,384,384) -> pat[b*576 + x*24+y][p1*48 + p2*3 + c] bf16
// ---------------------------------------------------------------------------
__global__ __launch_bounds__(64)
void patch_gather(const float* __restrict__ img, bf16* __restrict__ pat)
{
    const int bid = blockIdx.x;
    const int x  = bid % 24;
    const int p1 = (bid / 24) % 16;
    const int b  = bid / (24 * 16);
    __shared__ bf16 lds[24][48];
    const int lane = threadIdx.x;
    const int h = p1 * 24 + x;
    for (int c = 0; c < 3; ++c) {
        const float* row = img + ((long)(b * 3 + c) * 384 + h) * 384;
#pragma unroll
        for (int i = 0; i < 6; ++i) {
            const int wpix = lane + i * 64;
            const float v = row[wpix];
            const int y = wpix % 24, p2 = wpix / 24;
            lds[y][p2 * 3 + c] = __float2bfloat16(v);
        }
    }
    __syncthreads();
    for (int idx = lane; idx < 24 * 48; idx += 64) {
        const int y = idx / 48, j = idx % 48;
        pat[(long)(b * 576 + x * 24 + y) * 768 + p1 * 48 + j] = lds[y][j];
    }
}

// cls token row
__global__ __launch_bounds__(256)
void clsfill(const float* __restrict__ cls, const float* __restrict__ pos,
             float* __restrict__ tokf, bf16* __restrict__ xb)
{
    const int i = blockIdx.x * 256 + threadIdx.x;
    const int b = i >> 9, d = i & 511;
    const float v = cls[d] + pos[d];
    tokf[(long)b * TOKENS * DMODEL + d] = v;
    xb[(long)b * TOKENS * DMODEL + d] = __float2bfloat16(v);
}

// ---------------------------------------------------------------------------
// v (qkv permuted col 1024 + h*128 + d) -> vhT[(pair)*128 + d][t], t>=577 -> 0
// ---------------------------------------------------------------------------
__global__ __launch_bounds__(256)
void repack_v(const u16* __restrict__ qkv, u16* __restrict__ vhT)
{
    __shared__ u16 lds[64][136];
    const int bid = blockIdx.x;               // (pair, tt)
    const int tt = bid % 10, pair = bid / 10;
    const int b = pair >> 2, h = pair & 3;
    const int tid = threadIdx.x;
    const int tl = tid >> 2, seg = tid & 3;
    const long row = (long)b * TOKENS + tt * 64 + tl;
    const u16* src = qkv + row * 1536 + 1024 + h * 128 + seg * 32;
#pragma unroll
    for (int u = 0; u < 4; ++u)
        *(uint4*)&lds[tl][seg * 32 + u * 8] = *(const uint4*)&src[u * 8];
    __syncthreads();
    const int d = tid >> 1, th = (tid & 1) * 32;
    u16* dst = vhT + ((long)pair * 128 + d) * TPAD + tt * 64 + th;
#pragma unroll
    for (int blk = 0; blk < 4; ++blk) {
        uint4 pk; u16* pp = (u16*)&pk;
#pragma unroll
        for (int j = 0; j < 8; ++j) {
            const int t = tt * 64 + th + blk * 8 + j;
            pp[j] = (t < TOKENS) ? lds[th + blk * 8 + j][d] : (u16)0;
        }
        *(uint4*)&dst[blk * 8] = pk;
    }
}

// ---------------------------------------------------------------------------
// y = LN(xin + res)*g + b  -> outf (may alias res) and outb (bf16)
// ---------------------------------------------------------------------------
__global__ __launch_bounds__(256)
void resln(const float* __restrict__ xin, const float* __restrict__ res,
           const float* __restrict__ g, const float* __restrict__ b,
           float* __restrict__ outf, bf16* __restrict__ outb, int nrows)
{
    const int row = blockIdx.x * 4 + (threadIdx.x >> 6);
    if (row >= nrows) return;
    const int lane = threadIdx.x & 63;
    const float* p1 = xin + (long)row * DMODEL;
    const float* p2 = res + (long)row * DMODEL;
    float v[8];
    float s = 0.f;
#pragma unroll
    for (int i = 0; i < 8; ++i) { v[i] = p1[lane + i * 64] + p2[lane + i * 64]; s += v[i]; }
#pragma unroll
    for (int o = 32; o; o >>= 1) s += __shfl_xor(s, o);
    const float mean = s * (1.f / 512.f);
    float q = 0.f;
#pragma unroll
    for (int i = 0; i < 8; ++i) { const float d = v[i] - mean; q += d * d; }
#pragma unroll
    for (int o = 32; o; o >>= 1) q += __shfl_xor(q, o);
    const float rs = rsqrtf(q * (1.f / 512.f) + 1e-5f);
#pragma unroll
    for (int i = 0; i < 8; ++i) {
        const int c = lane + i * 64;
        const float o = (v[i] - mean) * rs * g[c] + b[c];
        outf[(long)row * DMODEL + c] = o;
        outb[(long)row * DMODEL + c] = __float2bfloat16(o);
    }
}

// Head: out[b][c] = tok[b*577][:] . Whead[:,c] + bhead[c]
__global__ __launch_bounds__(64)
void head_k(const float* __restrict__ tokf, const float* __restrict__ Wh,
            const float* __restrict__ bh, float* __restrict__ out)
{
    const int b = blockIdx.x;
    const int lane = threadIdx.x;
    const float* x = tokf + (long)b * TOKENS * DMODEL;
    float acc[10] = {};
#pragma unroll
    for (int i = 0; i < 8; ++i) {
        const int d = lane + i * 64;
        const float xv = x[d];
        const float* wr = Wh + (long)d * 10;
#pragma unroll
        for (int c = 0; c < 10; ++c) acc[c] += xv * wr[c];
    }
#pragma unroll
    for (int c = 0; c < 10; ++c)
#pragma unroll
        for (int o = 32; o; o >>= 1) acc[c] += __shfl_xor(acc[c], o);
    if (lane == 0) {
#pragma unroll
        for (int c = 0; c < 10; ++c) out[b * 10 + c] = acc[c] + bh[c];
    }
}

// ---------------------------------------------------------------------------
extern "C" void kernel_launch(void* const* d_in, const int* in_sizes, int n_in,
                              void* d_out, int out_size, void* d_ws, size_t ws_size,
                              hipStream_t stream)
{
    (void)in_sizes; (void)n_in; (void)out_size;
    const float* img    = (const float*)d_in[0];
    const float* Wpatch = (const float*)d_in[1];
    const float* bpatch = (const float*)d_in[2];
    const float* clstk  = (const float*)d_in[3];
    const float* pos    = (const float*)d_in[4];
    const float* Wqkv   = (const float*)d_in[5];
    const float* W0     = (const float*)d_in[6];
    const float* g1     = (const float*)d_in[7];
    const float* b1     = (const float*)d_in[8];
    const float* g2     = (const float*)d_in[9];
    const float* b2     = (const float*)d_in[10];
    const float* W1     = (const float*)d_in[11];
    const float* bb1    = (const float*)d_in[12];
    const float* W2     = (const float*)d_in[13];
    const float* bb2    = (const float*)d_in[14];
    const float* Whead  = (const float*)d_in[15];
    const float* bhead  = (const float*)d_in[16];

    // ---- pick the largest batch chunk that fits ws (M padded to 128) ----
    static const int cand[6] = {32, 16, 8, 4, 2, 1};
    int Bc = 0;
    size_t o_tokf=0, o_xb=0, o_R1=0, o_R2=0, o_ob=0, o_wp=0, o_wr=0;
    for (int ci = 0; ci < 6; ++ci) {
        const int bc = cand[ci];
        const long Mrows = (long)bc * TOKENS;
        const long Mpad  = ((Mrows + 127) / 128) * 128;
        size_t off = 0;
        auto take = [&](size_t sz) { size_t o = off; off += (sz + 255) & ~(size_t)255; return o; };
        size_t t_tokf = take((size_t)Mpad * 512 * 4);
        size_t t_xb   = take((size_t)Mpad * 512 * 2);
        size_t t_R1   = take((size_t)Mpad * 1536 * 2);          // pat | qkv
        size_t r2a = (size_t)bc * 4 * TPAD * 128 * 2;           // vhT
        size_t r2b = (size_t)Mpad * 512 * 4;                    // t1 (f32)
        size_t t_R2 = take(r2a > r2b ? r2a : r2b);
        size_t t_ob   = take((size_t)Mpad * 512 * 2);
        size_t t_wp   = take((size_t)512 * 768 * 2);
        size_t t_wr   = take((size_t)3145728 * 2);              // rotating layer weights
        if (off <= ws_size) {
            Bc = bc;
            o_tokf=t_tokf; o_xb=t_xb; o_R1=t_R1; o_R2=t_R2; o_ob=t_ob; o_wp=t_wp; o_wr=t_wr;
            break;
        }
    }
    if (Bc == 0) return;

    const long Mrows = (long)Bc * TOKENS;
    const long Mpad  = ((Mrows + 127) / 128) * 128;
    const int  NP    = Bc * 4;
    const int  gy    = (int)(Mpad / 128);
    const long patRows = ((long)Bc * 576 + 127) / 128 * 128;
    const int  nffn  = (int)((Mrows + 31) / 32);

    char* base = (char*)d_ws;
    float* tokf = (float*)(base + o_tokf);
    bf16*  xb   = (bf16*)(base + o_xb);
    char*  R1   = base + o_R1;
    char*  R2   = base + o_R2;
    bf16*  ob   = (bf16*)(base + o_ob);
    bf16*  wpT  = (bf16*)(base + o_wp);
    bf16*  wqkvT = (bf16*)(base + o_wr);
    bf16*  w0T   = wqkvT + 1536 * 512;
    bf16*  w1T   = w0T   + 512 * 512;
    bf16*  w2T   = w1T   + 2048 * 512;

    u16*  qkvb = (u16*)R1;
    bf16* pat  = (bf16*)R1;
    u16*  vhT  = (u16*)R2;
    float* t1  = (float*)R2;

    wtrans<false><<<dim3(512 / 32, 768 / 32), 256, 0, stream>>>(Wpatch, wpT, 768, 512);

    const int nchunks = 32 / Bc;
    for (int ch = 0; ch < nchunks; ++ch) {
        const float* img_c = img + (long)ch * Bc * 3 * 384 * 384;

        // embed
        hipMemsetAsync(xb, 0, (size_t)Mpad * 512 * 2, stream);   // pad rows -> exact 0
        clsfill<<<Bc * 2, 256, 0, stream>>>(clstk, pos, tokf, xb);
        patch_gather<<<Bc * 16 * 24, 64, 0, stream>>>(img_c, pat);
        gemm_bt<1><<<dim3(4, (int)(patRows / 128)), 256, 0, stream>>>(
            (const u16*)pat, 768, (const u16*)wpT, 768,
            tokf, xb, 512, bpatch, pos, 768, Bc * 576);

        for (int l = 0; l < 6; ++l) {
            // rotate this layer's weights to bf16 N x K (Wqkv column-permuted)
            wtrans<true ><<<dim3(1536 / 32, 512 / 32), 256, 0, stream>>>(
                Wqkv + (long)l * 512 * 1536, wqkvT, 512, 1536);
            wtrans<false><<<dim3(512 / 32, 512 / 32), 256, 0, stream>>>(
                W0 + (long)l * 512 * 512, w0T, 512, 512);
            wtrans<false><<<dim3(2048 / 32, 512 / 32), 256, 0, stream>>>(
                W1 + (long)l * 512 * 2048, w1T, 512, 2048);
            wtrans<false><<<dim3(512 / 32, 2048 / 32), 256, 0, stream>>>(
                W2 + (long)l * 2048 * 512, w2T, 2048, 512);

            // qkv = x @ Wqkv  (permuted cols: kk*512 + h*128 + d)
            gemm_bt<0><<<dim3(12, gy), 256, 0, stream>>>(
                (const u16*)xb, 512, (const u16*)wqkvT, 512,
                nullptr, (bf16*)qkvb, 1536, nullptr, nullptr, 512, (int)Mpad);

            repack_v<<<NP * 10, 256, 0, stream>>>(qkvb, vhT);
            attn_flash<<<dim3(5, NP), 256, 0, stream>>>(qkvb, vhT, ob);

            // proj: t1 = o @ W0   (t1 overwrites vhT — attention done)
            gemm_bt<0><<<dim3(4, gy), 256, 0, stream>>>(
                (const u16*)ob, 512, (const u16*)w0T, 512,
                t1, nullptr, 512, nullptr, nullptr, 512, (int)Mrows);
            // y = LN(t1 + x) -> tokf, xb
            resln<<<(int)((Mrows + 3) / 4), 256, 0, stream>>>(
                t1, tokf, g1 + l * 512, b1 + l * 512, tokf, xb, (int)Mrows);
            // fused FFN: x = LN(gelu(y@W1+bb1)@W2 + bb2 + y) -> tokf, xb
            ffn_fused<<<nffn, 512, 0, stream>>>(
                (const u16*)xb, tokf, (const u16*)w1T, (const u16*)w2T,
                bb1 + l * 2048, bb2 + l * 512, g2 + l * 512, b2 + l * 512,
                tokf, xb, (int)Mrows);
        }

        head_k<<<Bc, 64, 0, stream>>>(tokf, Whead, bhead, (float*)d_out + (long)ch * Bc * 10);
    }
}

// Round 8
// 3268.361 us; speedup vs baseline: 1.2767x; 1.2767x over previous
//
#include <hip/hip_runtime.h>
#include <hip/hip_bf16.h>

// ViT forward, MI355X. 8-phase counted-vmcnt 256x256 GEMM (m201-class template:
// K-half LDS slots, stage-1-half-tile-per-phase, vmcnt(4) never-drain, raw
// s_barrier, setprio) for all GEMMs; fused flash attention; f32 residual/LN.

typedef unsigned short u16;
typedef __hip_bfloat16 bf16;
typedef __bf16 bf16x8 __attribute__((ext_vector_type(8)));
typedef float f32x4 __attribute__((ext_vector_type(4)));

typedef const __attribute__((address_space(1))) void* gas_ptr;
typedef __attribute__((address_space(3))) void* las_ptr;

#define TOKENS 577
#define TPAD   640
#define DMODEL 512
#define SM_SCALE 0.08838834764831845f   /* 128^-0.5 */

static __device__ __forceinline__ u16 f2b(float v) {
    bf16 t = __float2bfloat16(v);
    return *(u16*)&t;
}

// ---------------------------------------------------------------------------
// 8-phase GEMM: C[M,N] = A[M,K] @ Bt[N,K]^T (+bias)(+gelu). BM=BN=256, BK=64.
// 512 threads = 8 waves (2M x 4N); per-wave C = 128x64 (8x4 frags).
// LDS: [2 dbuf][2 khalf] x 256rows x 32k per operand = 128 KB. K-tile t lives
// in dbuf t&1; tile t+1's half-tiles staged during tile t's 4 phases
// (A-kh0, B-kh0, A-kh1, B-kh1). Wait discipline (hand-verified issue stream):
//   ph2: vmcnt(4) certifies kh1(t) before ph3/4 reads
//   ph4: vmcnt(4) certifies kh0(t+1) before next tile's ph1/2 reads
// Raw s_barrier (no vmcnt(0) drain). XOR-swizzled k-octets (4-way residual).
// OUTMODE 0: plain. 1: patch-embed epilogue (row remap b*577+1+t, +pos).
// ---------------------------------------------------------------------------
template<int OUTMODE, bool GELU>
__global__ __launch_bounds__(512, 1)
void gemm8(const u16* __restrict__ A, int lda,
           const u16* __restrict__ Bt, int ldb,
           float* __restrict__ Cf, bf16* __restrict__ Cb, int ldc,
           const float* __restrict__ bias, const float* __restrict__ pos,
           int K, int rows_valid)
{
    __shared__ u16 Ash[2][2][256 * 32];   // [dbuf][khalf]  64 KB
    __shared__ u16 Bsh[2][2][256 * 32];   //                64 KB
    const int tid = threadIdx.x, wid = tid >> 6, lane = tid & 63;
    const int wm = wid >> 2, wn = wid & 3;
    const int lr = lane & 15, lg = lane >> 4;
    const u16* Ab = A + (long)blockIdx.y * 256 * lda;
    const u16* Bb = Bt + (long)blockIdx.x * 256 * ldb;
    const int srow = tid >> 2;                         // staging row (per issue-half)
    const int soct = ((tid & 3) ^ (srow & 3)) * 8;     // pre-swizzled global octet
    const int slot8 = (lg ^ (lr & 3)) * 8;             // swizzled read slot

    f32x4 acc[8][4] = {};

    auto stage = [&](u16* dst, const u16* src, int ld, int kt, int kh) {
#pragma unroll
        for (int i = 0; i < 2; ++i)
            __builtin_amdgcn_global_load_lds(
                (gas_ptr)(src + (long)(i * 128 + srow) * ld + kt * 64 + kh * 32 + soct),
                (las_ptr)(dst + (i * 512 + tid) * 8), 16, 0, 0);
    };

#define VMW(n) { asm volatile("s_waitcnt vmcnt(" #n ")" ::: "memory"); \
                 __builtin_amdgcn_sched_barrier(0); }
#define MFMA16(A0)                                                              \
    __builtin_amdgcn_s_setprio(1);                                             \
    _Pragma("unroll")                                                           \
    for (int m = 0; m < 4; ++m)                                                 \
        _Pragma("unroll")                                                       \
        for (int n = 0; n < 4; ++n)                                             \
            acc[(A0) + m][n] = __builtin_amdgcn_mfma_f32_16x16x32_bf16(         \
                af[m], bfr[n], acc[(A0) + m][n], 0, 0, 0);                      \
    __builtin_amdgcn_s_setprio(0);

    const int nt = K / 64;
    // prologue: tile 0's four half-tiles (A0,B0,A1,B1), then certify kh0(0)
    stage(&Ash[0][0][0], Ab, lda, 0, 0);
    stage(&Bsh[0][0][0], Bb, ldb, 0, 0);
    stage(&Ash[0][1][0], Ab, lda, 0, 1);
    stage(&Bsh[0][1][0], Bb, ldb, 0, 1);
    VMW(4);
    __builtin_amdgcn_s_barrier();

    for (int t = 0; t < nt; ++t) {
        const int db = t & 1;
        const bool nx = (t + 1 < nt);
        bf16x8 af[4], bfr[4];

        // ---- ph1: kh0, m-half0 ----
#pragma unroll
        for (int n = 0; n < 4; ++n)
            bfr[n] = *(const bf16x8*)&Bsh[db][0][(wn * 64 + n * 16 + lr) * 32 + slot8];
#pragma unroll
        for (int m = 0; m < 4; ++m)
            af[m] = *(const bf16x8*)&Ash[db][0][(wm * 128 + m * 16 + lr) * 32 + slot8];
        if (nx) stage(&Ash[db ^ 1][0][0], Ab, lda, t + 1, 0);
        __builtin_amdgcn_s_barrier();
        MFMA16(0)
        __builtin_amdgcn_s_barrier();

        // ---- ph2: kh0, m-half1 ----
#pragma unroll
        for (int m = 0; m < 4; ++m)
            af[m] = *(const bf16x8*)&Ash[db][0][(wm * 128 + 64 + m * 16 + lr) * 32 + slot8];
        if (nx) { stage(&Bsh[db ^ 1][0][0], Bb, ldb, t + 1, 0); VMW(4); }
        else    { VMW(0); }
        __builtin_amdgcn_s_barrier();
        MFMA16(4)
        __builtin_amdgcn_s_barrier();

        // ---- ph3: kh1, m-half0 ----
#pragma unroll
        for (int n = 0; n < 4; ++n)
            bfr[n] = *(const bf16x8*)&Bsh[db][1][(wn * 64 + n * 16 + lr) * 32 + slot8];
#pragma unroll
        for (int m = 0; m < 4; ++m)
            af[m] = *(const bf16x8*)&Ash[db][1][(wm * 128 + m * 16 + lr) * 32 + slot8];
        if (nx) stage(&Ash[db ^ 1][1][0], Ab, lda, t + 1, 1);
        __builtin_amdgcn_s_barrier();
        MFMA16(0)
        __builtin_amdgcn_s_barrier();

        // ---- ph4: kh1, m-half1 ----
#pragma unroll
        for (int m = 0; m < 4; ++m)
            af[m] = *(const bf16x8*)&Ash[db][1][(wm * 128 + 64 + m * 16 + lr) * 32 + slot8];
        if (nx) { stage(&Bsh[db ^ 1][1][0], Bb, ldb, t + 1, 1); VMW(4); }
        __builtin_amdgcn_s_barrier();
        MFMA16(4)
        __builtin_amdgcn_s_barrier();
    }
#undef MFMA16
#undef VMW

    const int cbase = blockIdx.x * 256 + wn * 64;
    const int rbase = blockIdx.y * 256 + wm * 128;
#pragma unroll
    for (int n = 0; n < 4; ++n) {
        const int c = cbase + n * 16 + lr;
        const float bval = bias ? bias[c] : 0.0f;
#pragma unroll
        for (int a = 0; a < 8; ++a) {
#pragma unroll
            for (int j = 0; j < 4; ++j) {
                const int r = rbase + a * 16 + lg * 4 + j;
                if (r >= rows_valid) continue;
                float v = acc[a][n][j] + bval;
                if constexpr (GELU) v = 0.5f * v * (1.0f + erff(v * 0.70710678118654752f));
                long idx;
                if constexpr (OUTMODE == 1) {
                    const int pb = r / 576, pt = r - pb * 576;
                    v += pos[(long)(1 + pt) * DMODEL + c];
                    idx = (long)(pb * TOKENS + 1 + pt) * ldc + c;
                } else {
                    idx = (long)r * ldc + c;
                }
                if (Cf) Cf[idx] = v;
                if (Cb) Cb[idx] = __float2bfloat16(v);
            }
        }
    }
}

// ---------------------------------------------------------------------------
// Fused flash attention (round-3 verified). Grid: (5 q-tiles, NP pairs).
// qkv layout (permuted): [row][ kk*512 + h*128 + d ], row = b*577 + t (+pad).
// ---------------------------------------------------------------------------
__global__ __launch_bounds__(256, 2)
void attn_flash(const u16* __restrict__ qkv, const u16* __restrict__ vhT,
                bf16* __restrict__ ob)
{
    __shared__ u16 ldsA[128 * 128];
    __shared__ u16 ldsB[128 * 128];
    const int tid = threadIdx.x;
    const int w = tid >> 6, lane = tid & 63;
    const int lr = lane & 15, lg = lane >> 4;
    const int pair = blockIdx.y;
    const int b = pair >> 2, h = pair & 3;
    const int q0 = blockIdx.x * 128;
    const long rowbase = (long)b * TOKENS;

    bf16x8 qf[2][4];
#pragma unroll
    for (int m = 0; m < 2; ++m)
#pragma unroll
        for (int kf = 0; kf < 4; ++kf) {
            const long r = rowbase + q0 + w * 32 + m * 16 + lr;
            qf[m][kf] = *(const bf16x8*)&qkv[r * 1536 + h * 128 + kf * 32 + lg * 8];
        }

    float mrun[2][4], lrun[2][4];
#pragma unroll
    for (int m = 0; m < 2; ++m)
#pragma unroll
        for (int j = 0; j < 4; ++j) { mrun[m][j] = -1e30f; lrun[m][j] = 0.f; }
    f32x4 oacc[2][8] = {};

    for (int kv0 = 0; kv0 < TPAD; kv0 += 128) {
        {
            const u16* kg = qkv + (rowbase + kv0) * 1536 + 512 + h * 128;
            const u16* vg = vhT + ((long)pair * 128) * TPAD + kv0;
#pragma unroll
            for (int p = 0; p < 8; ++p) {
                const int i = p * 16 + w * 4 + lg;
                __builtin_amdgcn_global_load_lds((gas_ptr)(kg + (long)i * 1536 + lr * 8),
                                                 (las_ptr)&ldsA[(p * 16 + w * 4) * 128], 16, 0, 0);
                __builtin_amdgcn_global_load_lds((gas_ptr)(vg + (long)i * TPAD + lr * 8),
                                                 (las_ptr)&ldsB[(p * 16 + w * 4) * 128], 16, 0, 0);
            }
        }
        __syncthreads();

        f32x4 s[2][8] = {};
#pragma unroll
        for (int kf = 0; kf < 4; ++kf) {
            bf16x8 bv[8];
#pragma unroll
            for (int n = 0; n < 8; ++n)
                bv[n] = *(const bf16x8*)&ldsA[(n * 16 + lr) * 128 + kf * 32 + lg * 8];
            __builtin_amdgcn_s_setprio(1);
#pragma unroll
            for (int m = 0; m < 2; ++m)
#pragma unroll
                for (int n = 0; n < 8; ++n)
                    s[m][n] = __builtin_amdgcn_mfma_f32_16x16x32_bf16(qf[m][kf], bv[n], s[m][n], 0, 0, 0);
            __builtin_amdgcn_s_setprio(0);
        }

        float sc[2][4];
#pragma unroll
        for (int m = 0; m < 2; ++m)
#pragma unroll
            for (int jj = 0; jj < 4; ++jj) {
                float mx = mrun[m][jj];
#pragma unroll
                for (int n = 0; n < 8; ++n) {
                    const int col = kv0 + n * 16 + lr;
                    float v = s[m][n][jj] * SM_SCALE;
                    v = (col < TOKENS) ? v : -1e30f;
                    s[m][n][jj] = v;
                    mx = fmaxf(mx, v);
                }
#pragma unroll
                for (int o = 1; o < 16; o <<= 1) mx = fmaxf(mx, __shfl_xor(mx, o));
                const float f = __expf(mrun[m][jj] - mx);
                sc[m][jj] = f;
                float sum = 0.f;
#pragma unroll
                for (int n = 0; n < 8; ++n) {
                    const float p = __expf(s[m][n][jj] - mx);
                    s[m][n][jj] = p;
                    sum += p;
                }
#pragma unroll
                for (int o = 1; o < 16; o <<= 1) sum += __shfl_xor(sum, o);
                lrun[m][jj] = lrun[m][jj] * f + sum;
                mrun[m][jj] = mx;
            }
#pragma unroll
        for (int m = 0; m < 2; ++m)
#pragma unroll
            for (int n = 0; n < 8; ++n)
#pragma unroll
                for (int jj = 0; jj < 4; ++jj) oacc[m][n][jj] *= sc[m][jj];

        __syncthreads();
#pragma unroll
        for (int m = 0; m < 2; ++m)
#pragma unroll
            for (int n = 0; n < 8; ++n)
#pragma unroll
                for (int jj = 0; jj < 4; ++jj)
                    ldsA[(w * 32 + m * 16 + lg * 4 + jj) * 128 + n * 16 + lr] = f2b(s[m][n][jj]);
        __syncthreads();

#pragma unroll
        for (int kf = 0; kf < 4; ++kf) {
            bf16x8 pa[2];
#pragma unroll
            for (int m = 0; m < 2; ++m)
                pa[m] = *(const bf16x8*)&ldsA[(w * 32 + m * 16 + lr) * 128 + kf * 32 + lg * 8];
            __builtin_amdgcn_s_setprio(1);
#pragma unroll
            for (int n = 0; n < 8; ++n) {
                const bf16x8 vb = *(const bf16x8*)&ldsB[(n * 16 + lr) * 128 + kf * 32 + lg * 8];
#pragma unroll
                for (int m = 0; m < 2; ++m)
                    oacc[m][n] = __builtin_amdgcn_mfma_f32_16x16x32_bf16(pa[m], vb, oacc[m][n], 0, 0, 0);
            }
            __builtin_amdgcn_s_setprio(0);
        }
        __syncthreads();
    }

#pragma unroll
    for (int m = 0; m < 2; ++m)
#pragma unroll
        for (int jj = 0; jj < 4; ++jj) {
            const float inv = 1.f / lrun[m][jj];
            const int q = q0 + w * 32 + m * 16 + lg * 4 + jj;
            if (q >= TOKENS) continue;
#pragma unroll
            for (int n = 0; n < 8; ++n)
                ob[(rowbase + q) * DMODEL + h * 128 + n * 16 + lr] =
                    __float2bfloat16(oacc[m][n][jj] * inv);
        }
}

// ---------------------------------------------------------------------------
// Weight transpose + f32->bf16:  WT[n][k] = bf16(W[k][n]).
// QKVPERM: output row n' = kk*512 + h*128 + d  for original col n = d*12+kk*4+h
// ---------------------------------------------------------------------------
template<bool QKVPERM>
__global__ __launch_bounds__(256)
void wtrans(const float* __restrict__ W, bf16* __restrict__ WT, int K, int N)
{
    __shared__ float tile[32][33];
    const int n0 = blockIdx.x * 32, k0 = blockIdx.y * 32;
    const int tx = threadIdx.x & 31, ty = threadIdx.x >> 5;
#pragma unroll
    for (int i = 0; i < 4; ++i)
        tile[ty + i * 8][tx] = W[(long)(k0 + ty + i * 8) * N + n0 + tx];
    __syncthreads();
#pragma unroll
    for (int i = 0; i < 4; ++i) {
        int n = n0 + ty + i * 8;
        if constexpr (QKVPERM) {
            const int d = n / 12, r = n % 12;
            n = (r >> 2) * 512 + (r & 3) * 128 + d;
        }
        WT[(long)n * K + k0 + tx] = __float2bfloat16(tile[tx][ty + i * 8]);
    }
}

// ---------------------------------------------------------------------------
// Patch gather: img (Bc,3,384,384) -> pat[b*576 + x*24+y][p1*48 + p2*3 + c] bf16
// ---------------------------------------------------------------------------
__global__ __launch_bounds__(64)
void patch_gather(const float* __restrict__ img, bf16* __restrict__ pat)
{
    const int bid = blockIdx.x;
    const int x  = bid % 24;
    const int p1 = (bid / 24) % 16;
    const int b  = bid / (24 * 16);
    __shared__ bf16 lds[24][48];
    const int lane = threadIdx.x;
    const int h = p1 * 24 + x;
    for (int c = 0; c < 3; ++c) {
        const float* row = img + ((long)(b * 3 + c) * 384 + h) * 384;
#pragma unroll
        for (int i = 0; i < 6; ++i) {
            const int wpix = lane + i * 64;
            const float v = row[wpix];
            const int y = wpix % 24, p2 = wpix / 24;
            lds[y][p2 * 3 + c] = __float2bfloat16(v);
        }
    }
    __syncthreads();
    for (int idx = lane; idx < 24 * 48; idx += 64) {
        const int y = idx / 48, j = idx % 48;
        pat[(long)(b * 576 + x * 24 + y) * 768 + p1 * 48 + j] = lds[y][j];
    }
}

// cls token row
__global__ __launch_bounds__(256)
void clsfill(const float* __restrict__ cls, const float* __restrict__ pos,
             float* __restrict__ tokf, bf16* __restrict__ xb)
{
    const int i = blockIdx.x * 256 + threadIdx.x;
    const int b = i >> 9, d = i & 511;
    const float v = cls[d] + pos[d];
    tokf[(long)b * TOKENS * DMODEL + d] = v;
    xb[(long)b * TOKENS * DMODEL + d] = __float2bfloat16(v);
}

// ---------------------------------------------------------------------------
// v (qkv permuted col 1024 + h*128 + d) -> vhT[(pair)*128 + d][t], t>=577 -> 0
// ---------------------------------------------------------------------------
__global__ __launch_bounds__(256)
void repack_v(const u16* __restrict__ qkv, u16* __restrict__ vhT)
{
    __shared__ u16 lds[64][136];
    const int bid = blockIdx.x;               // (pair, tt)
    const int tt = bid % 10, pair = bid / 10;
    const int b = pair >> 2, h = pair & 3;
    const int tid = threadIdx.x;
    const int tl = tid >> 2, seg = tid & 3;
    const long row = (long)b * TOKENS + tt * 64 + tl;
    const u16* src = qkv + row * 1536 + 1024 + h * 128 + seg * 32;
#pragma unroll
    for (int u = 0; u < 4; ++u)
        *(uint4*)&lds[tl][seg * 32 + u * 8] = *(const uint4*)&src[u * 8];
    __syncthreads();
    const int d = tid >> 1, th = (tid & 1) * 32;
    u16* dst = vhT + ((long)pair * 128 + d) * TPAD + tt * 64 + th;
#pragma unroll
    for (int blk = 0; blk < 4; ++blk) {
        uint4 pk; u16* pp = (u16*)&pk;
#pragma unroll
        for (int j = 0; j < 8; ++j) {
            const int t = tt * 64 + th + blk * 8 + j;
            pp[j] = (t < TOKENS) ? lds[th + blk * 8 + j][d] : (u16)0;
        }
        *(uint4*)&dst[blk * 8] = pk;
    }
}

// ---------------------------------------------------------------------------
// y = LN(xin + res)*g + b  -> outf (may alias res) and outb (bf16)
// ---------------------------------------------------------------------------
__global__ __launch_bounds__(256)
void resln(const float* __restrict__ xin, const float* __restrict__ res,
           const float* __restrict__ g, const float* __restrict__ b,
           float* __restrict__ outf, bf16* __restrict__ outb, int nrows)
{
    const int row = blockIdx.x * 4 + (threadIdx.x >> 6);
    if (row >= nrows) return;
    const int lane = threadIdx.x & 63;
    const float* p1 = xin + (long)row * DMODEL;
    const float* p2 = res + (long)row * DMODEL;
    float v[8];
    float s = 0.f;
#pragma unroll
    for (int i = 0; i < 8; ++i) { v[i] = p1[lane + i * 64] + p2[lane + i * 64]; s += v[i]; }
#pragma unroll
    for (int o = 32; o; o >>= 1) s += __shfl_xor(s, o);
    const float mean = s * (1.f / 512.f);
    float q = 0.f;
#pragma unroll
    for (int i = 0; i < 8; ++i) { const float d = v[i] - mean; q += d * d; }
#pragma unroll
    for (int o = 32; o; o >>= 1) q += __shfl_xor(q, o);
    const float rs = rsqrtf(q * (1.f / 512.f) + 1e-5f);
#pragma unroll
    for (int i = 0; i < 8; ++i) {
        const int c = lane + i * 64;
        const float o = (v[i] - mean) * rs * g[c] + b[c];
        outf[(long)row * DMODEL + c] = o;
        outb[(long)row * DMODEL + c] = __float2bfloat16(o);
    }
}

// Head: out[b][c] = tok[b*577][:] . Whead[:,c] + bhead[c]
__global__ __launch_bounds__(64)
void head_k(const float* __restrict__ tokf, const float* __restrict__ Wh,
            const float* __restrict__ bh, float* __restrict__ out)
{
    const int b = blockIdx.x;
    const int lane = threadIdx.x;
    const float* x = tokf + (long)b * TOKENS * DMODEL;
    float acc[10] = {};
#pragma unroll
    for (int i = 0; i < 8; ++i) {
        const int d = lane + i * 64;
        const float xv = x[d];
        const float* wr = Wh + (long)d * 10;
#pragma unroll
        for (int c = 0; c < 10; ++c) acc[c] += xv * wr[c];
    }
#pragma unroll
    for (int c = 0; c < 10; ++c)
#pragma unroll
        for (int o = 32; o; o >>= 1) acc[c] += __shfl_xor(acc[c], o);
    if (lane == 0) {
#pragma unroll
        for (int c = 0; c < 10; ++c) out[b * 10 + c] = acc[c] + bh[c];
    }
}

// ---------------------------------------------------------------------------
extern "C" void kernel_launch(void* const* d_in, const int* in_sizes, int n_in,
                              void* d_out, int out_size, void* d_ws, size_t ws_size,
                              hipStream_t stream)
{
    (void)in_sizes; (void)n_in; (void)out_size;
    const float* img    = (const float*)d_in[0];
    const float* Wpatch = (const float*)d_in[1];
    const float* bpatch = (const float*)d_in[2];
    const float* clstk  = (const float*)d_in[3];
    const float* pos    = (const float*)d_in[4];
    const float* Wqkv   = (const float*)d_in[5];
    const float* W0     = (const float*)d_in[6];
    const float* g1     = (const float*)d_in[7];
    const float* b1     = (const float*)d_in[8];
    const float* g2     = (const float*)d_in[9];
    const float* b2     = (const float*)d_in[10];
    const float* W1     = (const float*)d_in[11];
    const float* bb1    = (const float*)d_in[12];
    const float* W2     = (const float*)d_in[13];
    const float* bb2    = (const float*)d_in[14];
    const float* Whead  = (const float*)d_in[15];
    const float* bhead  = (const float*)d_in[16];

    // ---- pick the largest batch chunk that fits ws (M padded to 256) ----
    static const int cand[6] = {32, 16, 8, 4, 2, 1};
    int Bc = 0;
    size_t o_tokf=0, o_xb=0, o_R1=0, o_R2=0, o_ob=0, o_wp=0, o_wr=0;
    for (int ci = 0; ci < 6; ++ci) {
        const int bc = cand[ci];
        const long Mrows = (long)bc * TOKENS;
        const long Mpad  = ((Mrows + 255) / 256) * 256;
        size_t off = 0;
        auto take = [&](size_t sz) { size_t o = off; off += (sz + 255) & ~(size_t)255; return o; };
        size_t t_tokf = take((size_t)Mpad * 512 * 4);
        size_t t_xb   = take((size_t)Mpad * 512 * 2);
        size_t t_R1   = take((size_t)Mpad * 2048 * 2);          // pat | qkv | h1b
        size_t r2a = (size_t)bc * 4 * TPAD * 128 * 2;           // vhT
        size_t r2b = (size_t)Mpad * 512 * 4;                    // t1 (f32)
        size_t t_R2 = take(r2a > r2b ? r2a : r2b);
        size_t t_ob   = take((size_t)Mpad * 512 * 2);
        size_t t_wp   = take((size_t)512 * 768 * 2);
        size_t t_wr   = take((size_t)3145728 * 2);              // rotating layer weights
        if (off <= ws_size) {
            Bc = bc;
            o_tokf=t_tokf; o_xb=t_xb; o_R1=t_R1; o_R2=t_R2; o_ob=t_ob; o_wp=t_wp; o_wr=t_wr;
            break;
        }
    }
    if (Bc == 0) return;

    const long Mrows = (long)Bc * TOKENS;
    const long Mpad  = ((Mrows + 255) / 256) * 256;
    const int  NP    = Bc * 4;
    const int  gy    = (int)(Mpad / 256);
    const int  gyp   = (int)(((long)Bc * 576 + 255) / 256);

    char* base = (char*)d_ws;
    float* tokf = (float*)(base + o_tokf);
    bf16*  xb   = (bf16*)(base + o_xb);
    char*  R1   = base + o_R1;
    char*  R2   = base + o_R2;
    bf16*  ob   = (bf16*)(base + o_ob);
    bf16*  wpT  = (bf16*)(base + o_wp);
    bf16*  wqkvT = (bf16*)(base + o_wr);
    bf16*  w0T   = wqkvT + 1536 * 512;
    bf16*  w1T   = w0T   + 512 * 512;
    bf16*  w2T   = w1T   + 2048 * 512;

    u16*  qkvb = (u16*)R1;
    bf16* pat  = (bf16*)R1;
    u16*  h1b  = (u16*)R1;
    u16*  vhT  = (u16*)R2;
    float* t1  = (float*)R2;

    wtrans<false><<<dim3(512 / 32, 768 / 32), 256, 0, stream>>>(Wpatch, wpT, 768, 512);

    const int nchunks = 32 / Bc;
    for (int ch = 0; ch < nchunks; ++ch) {
        const float* img_c = img + (long)ch * Bc * 3 * 384 * 384;

        // embed
        hipMemsetAsync(xb, 0, (size_t)Mpad * 512 * 2, stream);   // pad rows -> exact 0
        clsfill<<<Bc * 2, 256, 0, stream>>>(clstk, pos, tokf, xb);
        patch_gather<<<Bc * 16 * 24, 64, 0, stream>>>(img_c, pat);
        gemm8<1, false><<<dim3(2, gyp), 512, 0, stream>>>(
            (const u16*)pat, 768, (const u16*)wpT, 768,
            tokf, xb, 512, bpatch, pos, 768, Bc * 576);

        for (int l = 0; l < 6; ++l) {
            // rotate this layer's weights to bf16 N x K (Wqkv column-permuted)
            wtrans<true ><<<dim3(1536 / 32, 512 / 32), 256, 0, stream>>>(
                Wqkv + (long)l * 512 * 1536, wqkvT, 512, 1536);
            wtrans<false><<<dim3(512 / 32, 512 / 32), 256, 0, stream>>>(
                W0 + (long)l * 512 * 512, w0T, 512, 512);
            wtrans<false><<<dim3(2048 / 32, 512 / 32), 256, 0, stream>>>(
                W1 + (long)l * 512 * 2048, w1T, 512, 2048);
            wtrans<false><<<dim3(512 / 32, 2048 / 32), 256, 0, stream>>>(
                W2 + (long)l * 2048 * 512, w2T, 2048, 512);

            // qkv = x @ Wqkv  (permuted cols: kk*512 + h*128 + d)
            gemm8<0, false><<<dim3(6, gy), 512, 0, stream>>>(
                (const u16*)xb, 512, (const u16*)wqkvT, 512,
                nullptr, (bf16*)qkvb, 1536, nullptr, nullptr, 512, (int)Mpad);

            repack_v<<<NP * 10, 256, 0, stream>>>(qkvb, vhT);
            attn_flash<<<dim3(5, NP), 256, 0, stream>>>(qkvb, vhT, ob);

            // proj: t1 = o @ W0   (t1 overwrites vhT — attention done)
            gemm8<0, false><<<dim3(2, gy), 512, 0, stream>>>(
                (const u16*)ob, 512, (const u16*)w0T, 512,
                t1, nullptr, 512, nullptr, nullptr, 512, (int)Mrows);
            // y = LN(t1 + x) -> tokf, xb
            resln<<<(int)((Mrows + 3) / 4), 256, 0, stream>>>(
                t1, tokf, g1 + l * 512, b1 + l * 512, tokf, xb, (int)Mrows);
            // h1 = gelu(y @ W1 + bb1)   (h1b overwrites qkv — dead)
            gemm8<0, true><<<dim3(8, gy), 512, 0, stream>>>(
                (const u16*)xb, 512, (const u16*)w1T, 512,
                nullptr, (bf16*)h1b, 2048, bb1 + l * 2048, nullptr, 512, (int)Mpad);
            // t1 = h1 @ W2 + bb2
            gemm8<0, false><<<dim3(2, gy), 512, 0, stream>>>(
                (const u16*)h1b, 2048, (const u16*)w2T, 2048,
                t1, nullptr, 512, bb2 + l * 512, nullptr, 2048, (int)Mrows);
            // x = LN(t1 + y) -> tokf, xb
            resln<<<(int)((Mrows + 3) / 4), 256, 0, stream>>>(
                t1, tokf, g2 + l * 512, b2 + l * 512, tokf, xb, (int)Mrows);
        }

        head_k<<<Bc, 64, 0, stream>>>(tokf, Whead, bhead, (float*)d_out + (long)ch * Bc * 10);
    }
}